// Round 22
// baseline (135.704 us; speedup 1.0000x reference)
//
#include <hip/hip_runtime.h>
#include <hip/hip_bf16.h>

#define D_MODEL 1024
#define SEQ     2048
#define NH      16
#define HD      64
#define M_TOK   4096
#define THREE_D 3072

using bf16x8 = __bf16 __attribute__((ext_vector_type(8)));
using bf16x4 = __bf16 __attribute__((ext_vector_type(4)));
using f32x4  = float  __attribute__((ext_vector_type(4)));

typedef __attribute__((address_space(3))) uint32_t lds_u32;
typedef const __attribute__((address_space(1))) uint32_t glb_u32;

// ---------------- fused prep: x cast (blocks 0..4095), w_qkv T (4096..4863), w_proj T (4864..5119) ----------------
__global__ __launch_bounds__(256) void prep_kernel(const float* __restrict__ x,
                                                   const float* __restrict__ w_qkv,
                                                   const float* __restrict__ w_proj,
                                                   __bf16* __restrict__ xb,
                                                   __bf16* __restrict__ wqkvT,
                                                   __bf16* __restrict__ wprojT) {
  const int bid = blockIdx.x;
  if (bid < 4096) {
    int i = bid * 256 + threadIdx.x;
    float4 f = reinterpret_cast<const float4*>(x)[i];
    bf16x4 o;
    o[0] = (__bf16)f.x; o[1] = (__bf16)f.y; o[2] = (__bf16)f.z; o[3] = (__bf16)f.w;
    reinterpret_cast<bf16x4*>(xb)[i] = o;
    return;
  }
  __shared__ float tile[64][65];
  const float* in; __bf16* out; int R, C, t;
  if (bid < 4864) { in = w_qkv;  out = wqkvT;  R = D_MODEL; C = THREE_D; t = bid - 4096; }
  else            { in = w_proj; out = wprojT; R = D_MODEL; C = D_MODEL; t = bid - 4864; }
  const int nCx = C / 64;
  const int c0 = (t % nCx) * 64, r0 = (t / nCx) * 64;
  const int tx = threadIdx.x & 63, ty = threadIdx.x >> 6;
#pragma unroll
  for (int i = 0; i < 16; ++i) {
    int r = ty + i * 4;
    tile[r][tx] = in[(size_t)(r0 + r) * C + c0 + tx];
  }
  __syncthreads();
#pragma unroll
  for (int i = 0; i < 16; ++i) {
    int r = ty + i * 4;
    out[(size_t)(c0 + r) * R + r0 + tx] = (__bf16)tile[tx][r];
  }
}

// ---------------- QKV GEMM: 128x128, BK=32, 3-deep pipeline (R20-exact) ----------------
// Q TRANSPOSED [bh][d][s] scaled 0.125*log2(e); K [bh][s][d]; V transposed [bh][d][s].
__global__ __launch_bounds__(256, 3) void gemm_qkv(const __bf16* __restrict__ A,
                                                   const __bf16* __restrict__ BT,
                                                   const float* __restrict__ bias,
                                                   __bf16* __restrict__ qt, __bf16* __restrict__ kb,
                                                   __bf16* __restrict__ vb) {
  __shared__ __bf16 As[3][128 * 32];
  __shared__ __bf16 Bs[3][128 * 32];
  const int Kdim = D_MODEL;
  const int tid  = threadIdx.x;
  const int lane = tid & 63, wave = tid >> 6;
  const int lr = lane & 15, lg = lane >> 4;
  const int wm = (wave >> 1) * 64, wn = (wave & 1) * 64;

  const int f   = blockIdx.x;
  const int swz = (f & 7) * 96 + (f >> 3);
  const int m0  = (swz / 24) * 128, n0 = (swz % 24) * 128;

  const int srow = tid >> 2, scol = (tid & 3) * 8;

  f32x4 acc[4][4] = {};

  const __bf16* aSrc = A  + (size_t)(m0 + srow) * Kdim + scol;
  const __bf16* bSrc = BT + (size_t)(n0 + srow) * Kdim + scol;

  auto stage = [&](int p, int k0) {
    __builtin_amdgcn_global_load_lds((glb_u32*)(aSrc + k0),              (lds_u32*)(As[p] + wave * 512),        16, 0, 0);
    __builtin_amdgcn_global_load_lds((glb_u32*)(aSrc + 64 * Kdim + k0), (lds_u32*)(As[p] + wave * 512 + 2048), 16, 0, 0);
    __builtin_amdgcn_global_load_lds((glb_u32*)(bSrc + k0),              (lds_u32*)(Bs[p] + wave * 512),        16, 0, 0);
    __builtin_amdgcn_global_load_lds((glb_u32*)(bSrc + 64 * Kdim + k0), (lds_u32*)(Bs[p] + wave * 512 + 2048), 16, 0, 0);
  };

  const int nk = Kdim / 32;
  stage(0, 0);
  stage(1, 32);
  for (int kk = 0; kk < nk; ++kk) {
    const int cur = kk % 3;
    if (kk + 2 < nk) {
      stage((kk + 2) % 3, (kk + 2) * 32);
      asm volatile("s_waitcnt vmcnt(8)" ::: "memory");
    } else if (kk + 1 < nk) {
      asm volatile("s_waitcnt vmcnt(4)" ::: "memory");
    } else {
      asm volatile("s_waitcnt vmcnt(0)" ::: "memory");
    }
    __builtin_amdgcn_s_barrier();

    bf16x8 af[4], bfv[4];
#pragma unroll
    for (int i = 0; i < 4; ++i) af[i]  = *reinterpret_cast<const bf16x8*>(&As[cur][(wm + i * 16 + lr) * 32 + lg * 8]);
#pragma unroll
    for (int j = 0; j < 4; ++j) bfv[j] = *reinterpret_cast<const bf16x8*>(&Bs[cur][(wn + j * 16 + lr) * 32 + lg * 8]);
#pragma unroll
    for (int i = 0; i < 4; ++i)
#pragma unroll
      for (int j = 0; j < 4; ++j)
        acc[i][j] = __builtin_amdgcn_mfma_f32_16x16x32_bf16(af[i], bfv[j], acc[i][j], 0, 0, 0);

    asm volatile("s_waitcnt lgkmcnt(0)" ::: "memory");
    __builtin_amdgcn_s_barrier();
  }

  const int reg = n0 >> 10;
  if (reg != 1) {
    __bf16* dst = (reg == 0) ? qt : vb;
    const float scl = (reg == 0) ? 0.18033688011112042f : 1.0f;   // 0.125*log2(e) for Q
#pragma unroll
    for (int j = 0; j < 4; ++j) {
      const int gc = n0 + wn + j * 16 + lr;
      const float bv = bias[gc];
      const int rem = gc & 1023, h = rem >> 6, d = rem & 63;
#pragma unroll
      for (int i = 0; i < 4; ++i) {
        const int gr0 = m0 + wm + i * 16 + lg * 4;
        const int b = gr0 >> 11, s0 = gr0 & 2047;
        bf16x4 v4;
#pragma unroll
        for (int ii = 0; ii < 4; ++ii) v4[ii] = (__bf16)((acc[i][j][ii] + bv) * scl);
        *reinterpret_cast<bf16x4*>(&dst[(((size_t)(b * NH + h)) * HD + d) * SEQ + s0]) = v4;
      }
    }
  } else {
#pragma unroll
    for (int i = 0; i < 4; ++i) {
#pragma unroll
      for (int j = 0; j < 4; ++j) {
        const int gc = n0 + wn + j * 16 + lr;
        const float bv = bias[gc];
        const int rem = gc & 1023, h = rem >> 6, d = rem & 63;
#pragma unroll
        for (int ii = 0; ii < 4; ++ii) {
          const int gr = m0 + wm + i * 16 + lg * 4 + ii;
          const int b = gr >> 11, s = gr & 2047;
          kb[(((size_t)(b * NH + h)) * SEQ + s) * HD + d] = (__bf16)(acc[i][j][ii] + bv);
        }
      }
    }
  }
}

// ---------------- proj GEMM: 64x128 tile, BK=32, 3-deep pipeline (R20-exact) ----------------
__global__ __launch_bounds__(256, 4) void gemm_proj(const __bf16* __restrict__ A,
                                                    const __bf16* __restrict__ BT,
                                                    const float* __restrict__ bias,
                                                    float* __restrict__ fout) {
  __shared__ __bf16 As[3][64 * 32];
  __shared__ __bf16 Bs[3][128 * 32];
  const int Kdim = D_MODEL;
  const int tid  = threadIdx.x;
  const int lane = tid & 63, wave = tid >> 6;
  const int lr = lane & 15, lg = lane >> 4;
  const int wm = (wave >> 1) * 32, wn = (wave & 1) * 64;
  const int n0 = blockIdx.x * 128, m0 = blockIdx.y * 64;
  const int srow = tid >> 2, scol = (tid & 3) * 8;

  f32x4 acc[2][4] = {};

  const __bf16* aSrc = A  + (size_t)(m0 + srow) * Kdim + scol;
  const __bf16* bSrc = BT + (size_t)(n0 + srow) * Kdim + scol;

  auto stage = [&](int p, int k0) {
    __builtin_amdgcn_global_load_lds((glb_u32*)(aSrc + k0),              (lds_u32*)(As[p] + wave * 512),        16, 0, 0);
    __builtin_amdgcn_global_load_lds((glb_u32*)(bSrc + k0),              (lds_u32*)(Bs[p] + wave * 512),        16, 0, 0);
    __builtin_amdgcn_global_load_lds((glb_u32*)(bSrc + 64 * Kdim + k0), (lds_u32*)(Bs[p] + wave * 512 + 2048), 16, 0, 0);
  };

  const int nk = Kdim / 32;
  stage(0, 0);
  stage(1, 32);
  for (int kk = 0; kk < nk; ++kk) {
    const int cur = kk % 3;
    if (kk + 2 < nk) {
      stage((kk + 2) % 3, (kk + 2) * 32);
      asm volatile("s_waitcnt vmcnt(6)" ::: "memory");
    } else if (kk + 1 < nk) {
      asm volatile("s_waitcnt vmcnt(3)" ::: "memory");
    } else {
      asm volatile("s_waitcnt vmcnt(0)" ::: "memory");
    }
    __builtin_amdgcn_s_barrier();

    bf16x8 af[2], bfv[4];
#pragma unroll
    for (int i = 0; i < 2; ++i) af[i]  = *reinterpret_cast<const bf16x8*>(&As[cur][(wm + i * 16 + lr) * 32 + lg * 8]);
#pragma unroll
    for (int j = 0; j < 4; ++j) bfv[j] = *reinterpret_cast<const bf16x8*>(&Bs[cur][(wn + j * 16 + lr) * 32 + lg * 8]);
#pragma unroll
    for (int i = 0; i < 2; ++i)
#pragma unroll
      for (int j = 0; j < 4; ++j)
        acc[i][j] = __builtin_amdgcn_mfma_f32_16x16x32_bf16(af[i], bfv[j], acc[i][j], 0, 0, 0);

    asm volatile("s_waitcnt lgkmcnt(0)" ::: "memory");
    __builtin_amdgcn_s_barrier();
  }

#pragma unroll
  for (int i = 0; i < 2; ++i) {
#pragma unroll
    for (int j = 0; j < 4; ++j) {
      const int gc = n0 + wn + j * 16 + lr;
      const float bv = bias[gc];
#pragma unroll
      for (int ii = 0; ii < 4; ++ii) {
        const int gr = m0 + wm + i * 16 + lg * 4 + ii;
        fout[(size_t)gr * D_MODEL + gc] = acc[i][j][ii] + bv;
      }
    }
  }
}

// ---------------- causal flash attention: 4 waves/block, QBLK=64, V direct-from-L2 ----------------
// K staged in LDS (double-buffered, swizzled); V fragments loaded straight from global
// (VT [bh][d][s] makes each fragment a contiguous 16B load; issued before QK so latency
// hides under softmax+MFMA). Halves per-tile LDS traffic vs the staged-V version.
__global__ __launch_bounds__(256, 4) void attn_kernel(const __bf16* __restrict__ QT,
                                                      const __bf16* __restrict__ K,
                                                      const __bf16* __restrict__ VT,
                                                      __bf16* __restrict__ AO) {
  __shared__ __bf16 Kb[2][64 * 64];   // 8 KB each
  __shared__ __bf16 Ps[4][16 * 64];   // 8 KB -> total 24 KB

  const int tid  = threadIdx.x;
  const int lane = tid & 63, wave = tid >> 6;
  const int lr = lane & 15, lg = lane >> 4;

  const int f  = blockIdx.x;
  const int c  = f & 7;
  const int u  = f >> 3;
  const int bh = c * 4 + (u & 3);
  const int s2 = u >> 2, grp = s2 >> 3, r = s2 & 7;
  const int qblk = (grp == 0) ? (31 - r) : (grp == 1) ? r : (grp == 2) ? (39 - s2) : (s2 - 16);

  const int q0 = qblk * 64 + wave * 16;
  const size_t base = (size_t)bh * SEQ * HD;
  const char* Kg = (const char*)(K + base);

  // Q fragment from Qt[bh][d][s] (once per block)
  bf16x8 qf[2];
#pragma unroll
  for (int kc = 0; kc < 2; ++kc) {
    bf16x8 v;
#pragma unroll
    for (int j = 0; j < 8; ++j)
      v[j] = QT[base + (size_t)(kc * 32 + lg * 8 + j) * SEQ + q0 + lr];
    qf[kc] = v;
  }

  int pAddr[4][4];
#pragma unroll
  for (int n = 0; n < 4; ++n)
#pragma unroll
    for (int ii = 0; ii < 4; ++ii) {
      const int row = lg * 4 + ii;
      pAddr[n][ii] = row * 64 + (((n * 2 + (lr >> 3)) ^ (row & 7)) << 3) + (lr & 7);
    }

  float lrun[4] = {0.f, 0.f, 0.f, 0.f};
  f32x4 o[4] = {};

  const int nt = qblk + 1;
  const int nmaxF = (wave | 1) + 1;

  // stage K only: wave covers rows [wave*16, wave*16+16)
  auto stage = [&](int bufp, int t) {
    const int k0 = t * 64;
#pragma unroll
    for (int p = 0; p < 2; ++p) {
      const int row = wave * 16 + p * 8 + (lane >> 3);
      const int srcOff = (k0 + row) * 128 + (((lane & 7) ^ (row & 7)) << 4);
      __builtin_amdgcn_global_load_lds((glb_u32*)(Kg + srcOff),
                                       (lds_u32*)&Kb[bufp][(wave * 16 + p * 8) * 64], 16, 0, 0);
    }
  };

  stage(0, 0);
  asm volatile("s_waitcnt vmcnt(0)" ::: "memory");
  __syncthreads();

  for (int t = 0; t < nt; ++t) {
    const int p = t & 1;
    const int k0 = t * 64;
    const bool last = (t == nt - 1);
    const int nmax = last ? nmaxF : 4;
    const int kcmax = nmax >> 1;

    // ---- V fragments direct from global (issued first; latency hides under QK+softmax) ----
    bf16x8 vf[2][4];
#pragma unroll
    for (int kc = 0; kc < 2; ++kc)
      if (kc < kcmax)
#pragma unroll
        for (int nd = 0; nd < 4; ++nd)
          vf[kc][nd] = *reinterpret_cast<const bf16x8*>(
              VT + base + (size_t)(nd * 16 + lr) * SEQ + k0 + kc * 32 + lg * 8);

    // ---- prefetch next K tile ----
    if (t + 1 < nt) stage(p ^ 1, t + 1);

    const __bf16* Kt = Kb[p];

    f32x4 s[4] = {};
    __builtin_amdgcn_s_setprio(1);
#pragma unroll
    for (int kc = 0; kc < 2; ++kc) {
#pragma unroll
      for (int n = 0; n < 4; ++n)
        if (n < nmax) {
          bf16x8 kf = *reinterpret_cast<const bf16x8*>(
              &Kt[(n * 16 + lr) * 64 + (((kc * 4 + lg) ^ (lr & 7)) << 3)]);
          s[n] = __builtin_amdgcn_mfma_f32_16x16x32_bf16(qf[kc], kf, s[n], 0, 0, 0);
        }
    }
    __builtin_amdgcn_s_setprio(0);

    if (last) {
#pragma unroll
      for (int n = 0; n < 4; ++n)
        if (n < nmax)
#pragma unroll
          for (int ii = 0; ii < 4; ++ii) {
            int qg = q0 + lg * 4 + ii;
            int kg = k0 + n * 16 + lr;
            if (kg > qg) s[n][ii] = -__builtin_inff();
          }
    }

#pragma unroll
    for (int n = 0; n < 4; ++n)
      if (n < nmax)
#pragma unroll
        for (int ii = 0; ii < 4; ++ii) {
          float pv = __builtin_amdgcn_exp2f(s[n][ii]);
          lrun[ii] += pv;
          Ps[wave][pAddr[n][ii]] = (__bf16)pv;
        }

    __builtin_amdgcn_s_setprio(1);
#pragma unroll
    for (int kc = 0; kc < 2; ++kc)
      if (kc < kcmax) {
        bf16x8 pa = *reinterpret_cast<const bf16x8*>(
            &Ps[wave][lr * 64 + (((kc * 4 + lg) ^ (lr & 7)) << 3)]);
#pragma unroll
        for (int nd = 0; nd < 4; ++nd)
          o[nd] = __builtin_amdgcn_mfma_f32_16x16x32_bf16(pa, vf[kc][nd], o[nd], 0, 0, 0);
      }
    __builtin_amdgcn_s_setprio(0);

    asm volatile("s_waitcnt vmcnt(0)" ::: "memory");   // K(t+1) staged before next tile
    __syncthreads();
  }

#pragma unroll
  for (int off = 1; off <= 8; off <<= 1)
#pragma unroll
    for (int ii = 0; ii < 4; ++ii) lrun[ii] += __shfl_xor(lrun[ii], off, 64);

  const int b = bh >> 4, h = bh & 15;
  float rl[4];
#pragma unroll
  for (int ii = 0; ii < 4; ++ii) rl[ii] = 1.f / lrun[ii];
#pragma unroll
  for (int nd = 0; nd < 4; ++nd)
#pragma unroll
    for (int ii = 0; ii < 4; ++ii) {
      int row = q0 + lg * 4 + ii;
      AO[((size_t)(b * SEQ) + row) * D_MODEL + h * HD + nd * 16 + lr] = (__bf16)(o[nd][ii] * rl[ii]);
    }
}

// ---------------- launch ----------------
extern "C" void kernel_launch(void* const* d_in, const int* in_sizes, int n_in,
                              void* d_out, int out_size, void* d_ws, size_t ws_size,
                              hipStream_t stream) {
  const float* x      = (const float*)d_in[0];
  const float* w_qkv  = (const float*)d_in[1];
  const float* b_qkv  = (const float*)d_in[2];
  const float* w_proj = (const float*)d_in[3];
  const float* b_proj = (const float*)d_in[4];
  float* out = (float*)d_out;

  char* ws = (char*)d_ws;
  __bf16* xb     = (__bf16*)(ws);                    // 8 MiB
  __bf16* wqkvT  = (__bf16*)(ws + 8388608);          // 6 MiB
  __bf16* wprojT = (__bf16*)(ws + 14680064);         // 2 MiB
  __bf16* qtb    = (__bf16*)(ws + 16777216);         // 8 MiB (transposed Q)
  __bf16* kb     = (__bf16*)(ws + 25165824);         // 8 MiB
  __bf16* vtb    = (__bf16*)(ws + 33554432);         // 8 MiB (transposed V)
  __bf16* ao     = (__bf16*)(ws + 41943040);         // 8 MiB

  prep_kernel<<<5120, 256, 0, stream>>>(x, w_qkv, w_proj, xb, wqkvT, wprojT);

  gemm_qkv<<<768, 256, 0, stream>>>(xb, wqkvT, b_qkv, qtb, kb, vtb);

  attn_kernel<<<1024, 256, 0, stream>>>(qtb, kb, vtb, ao);

  gemm_proj<<<dim3(D_MODEL / 128, M_TOK / 64), 256, 0, stream>>>(
      ao, wprojT, b_proj, out);
}

// Round 23
// 135.620 us; speedup vs baseline: 1.0006x; 1.0006x over previous
//
#include <hip/hip_runtime.h>
#include <hip/hip_bf16.h>

#define D_MODEL 1024
#define SEQ     2048
#define NH      16
#define HD      64
#define M_TOK   4096
#define THREE_D 3072

using bf16x8 = __bf16 __attribute__((ext_vector_type(8)));
using bf16x4 = __bf16 __attribute__((ext_vector_type(4)));
using f32x4  = float  __attribute__((ext_vector_type(4)));

typedef __attribute__((address_space(3))) uint32_t lds_u32;
typedef const __attribute__((address_space(1))) uint32_t glb_u32;

// ---------------- fused prep: x cast (blocks 0..4095), w_qkv T (4096..4863), w_proj T (4864..5119) ----------------
__global__ __launch_bounds__(256) void prep_kernel(const float* __restrict__ x,
                                                   const float* __restrict__ w_qkv,
                                                   const float* __restrict__ w_proj,
                                                   __bf16* __restrict__ xb,
                                                   __bf16* __restrict__ wqkvT,
                                                   __bf16* __restrict__ wprojT) {
  const int bid = blockIdx.x;
  if (bid < 4096) {
    int i = bid * 256 + threadIdx.x;
    float4 f = reinterpret_cast<const float4*>(x)[i];
    bf16x4 o;
    o[0] = (__bf16)f.x; o[1] = (__bf16)f.y; o[2] = (__bf16)f.z; o[3] = (__bf16)f.w;
    reinterpret_cast<bf16x4*>(xb)[i] = o;
    return;
  }
  __shared__ float tile[64][65];
  const float* in; __bf16* out; int R, C, t;
  if (bid < 4864) { in = w_qkv;  out = wqkvT;  R = D_MODEL; C = THREE_D; t = bid - 4096; }
  else            { in = w_proj; out = wprojT; R = D_MODEL; C = D_MODEL; t = bid - 4864; }
  const int nCx = C / 64;
  const int c0 = (t % nCx) * 64, r0 = (t / nCx) * 64;
  const int tx = threadIdx.x & 63, ty = threadIdx.x >> 6;
#pragma unroll
  for (int i = 0; i < 16; ++i) {
    int r = ty + i * 4;
    tile[r][tx] = in[(size_t)(r0 + r) * C + c0 + tx];
  }
  __syncthreads();
#pragma unroll
  for (int i = 0; i < 16; ++i) {
    int r = ty + i * 4;
    out[(size_t)(c0 + r) * R + r0 + tx] = (__bf16)tile[tx][r];
  }
}

// ---------------- QKV GEMM: 128x128, BK=32, 3-deep pipeline (R20-exact) ----------------
// Q TRANSPOSED [bh][d][s] scaled 0.125*log2(e); K [bh][s][d]; V transposed [bh][d][s].
__global__ __launch_bounds__(256, 3) void gemm_qkv(const __bf16* __restrict__ A,
                                                   const __bf16* __restrict__ BT,
                                                   const float* __restrict__ bias,
                                                   __bf16* __restrict__ qt, __bf16* __restrict__ kb,
                                                   __bf16* __restrict__ vb) {
  __shared__ __bf16 As[3][128 * 32];
  __shared__ __bf16 Bs[3][128 * 32];
  const int Kdim = D_MODEL;
  const int tid  = threadIdx.x;
  const int lane = tid & 63, wave = tid >> 6;
  const int lr = lane & 15, lg = lane >> 4;
  const int wm = (wave >> 1) * 64, wn = (wave & 1) * 64;

  const int f   = blockIdx.x;
  const int swz = (f & 7) * 96 + (f >> 3);
  const int m0  = (swz / 24) * 128, n0 = (swz % 24) * 128;

  const int srow = tid >> 2, scol = (tid & 3) * 8;

  f32x4 acc[4][4] = {};

  const __bf16* aSrc = A  + (size_t)(m0 + srow) * Kdim + scol;
  const __bf16* bSrc = BT + (size_t)(n0 + srow) * Kdim + scol;

  auto stage = [&](int p, int k0) {
    __builtin_amdgcn_global_load_lds((glb_u32*)(aSrc + k0),              (lds_u32*)(As[p] + wave * 512),        16, 0, 0);
    __builtin_amdgcn_global_load_lds((glb_u32*)(aSrc + 64 * Kdim + k0), (lds_u32*)(As[p] + wave * 512 + 2048), 16, 0, 0);
    __builtin_amdgcn_global_load_lds((glb_u32*)(bSrc + k0),              (lds_u32*)(Bs[p] + wave * 512),        16, 0, 0);
    __builtin_amdgcn_global_load_lds((glb_u32*)(bSrc + 64 * Kdim + k0), (lds_u32*)(Bs[p] + wave * 512 + 2048), 16, 0, 0);
  };

  const int nk = Kdim / 32;
  stage(0, 0);
  stage(1, 32);
  for (int kk = 0; kk < nk; ++kk) {
    const int cur = kk % 3;
    if (kk + 2 < nk) {
      stage((kk + 2) % 3, (kk + 2) * 32);
      asm volatile("s_waitcnt vmcnt(8)" ::: "memory");
    } else if (kk + 1 < nk) {
      asm volatile("s_waitcnt vmcnt(4)" ::: "memory");
    } else {
      asm volatile("s_waitcnt vmcnt(0)" ::: "memory");
    }
    __builtin_amdgcn_s_barrier();

    bf16x8 af[4], bfv[4];
#pragma unroll
    for (int i = 0; i < 4; ++i) af[i]  = *reinterpret_cast<const bf16x8*>(&As[cur][(wm + i * 16 + lr) * 32 + lg * 8]);
#pragma unroll
    for (int j = 0; j < 4; ++j) bfv[j] = *reinterpret_cast<const bf16x8*>(&Bs[cur][(wn + j * 16 + lr) * 32 + lg * 8]);
#pragma unroll
    for (int i = 0; i < 4; ++i)
#pragma unroll
      for (int j = 0; j < 4; ++j)
        acc[i][j] = __builtin_amdgcn_mfma_f32_16x16x32_bf16(af[i], bfv[j], acc[i][j], 0, 0, 0);

    asm volatile("s_waitcnt lgkmcnt(0)" ::: "memory");
    __builtin_amdgcn_s_barrier();
  }

  const int reg = n0 >> 10;
  if (reg != 1) {
    __bf16* dst = (reg == 0) ? qt : vb;
    const float scl = (reg == 0) ? 0.18033688011112042f : 1.0f;   // 0.125*log2(e) for Q
#pragma unroll
    for (int j = 0; j < 4; ++j) {
      const int gc = n0 + wn + j * 16 + lr;
      const float bv = bias[gc];
      const int rem = gc & 1023, h = rem >> 6, d = rem & 63;
#pragma unroll
      for (int i = 0; i < 4; ++i) {
        const int gr0 = m0 + wm + i * 16 + lg * 4;
        const int b = gr0 >> 11, s0 = gr0 & 2047;
        bf16x4 v4;
#pragma unroll
        for (int ii = 0; ii < 4; ++ii) v4[ii] = (__bf16)((acc[i][j][ii] + bv) * scl);
        *reinterpret_cast<bf16x4*>(&dst[(((size_t)(b * NH + h)) * HD + d) * SEQ + s0]) = v4;
      }
    }
  } else {
#pragma unroll
    for (int i = 0; i < 4; ++i) {
#pragma unroll
      for (int j = 0; j < 4; ++j) {
        const int gc = n0 + wn + j * 16 + lr;
        const float bv = bias[gc];
        const int rem = gc & 1023, h = rem >> 6, d = rem & 63;
#pragma unroll
        for (int ii = 0; ii < 4; ++ii) {
          const int gr = m0 + wm + i * 16 + lg * 4 + ii;
          const int b = gr >> 11, s = gr & 2047;
          kb[(((size_t)(b * NH + h)) * SEQ + s) * HD + d] = (__bf16)(acc[i][j][ii] + bv);
        }
      }
    }
  }
}

// ---------------- proj GEMM: 64x128 tile, BK=32, 3-deep pipeline (R20-exact) ----------------
__global__ __launch_bounds__(256, 4) void gemm_proj(const __bf16* __restrict__ A,
                                                    const __bf16* __restrict__ BT,
                                                    const float* __restrict__ bias,
                                                    float* __restrict__ fout) {
  __shared__ __bf16 As[3][64 * 32];
  __shared__ __bf16 Bs[3][128 * 32];
  const int Kdim = D_MODEL;
  const int tid  = threadIdx.x;
  const int lane = tid & 63, wave = tid >> 6;
  const int lr = lane & 15, lg = lane >> 4;
  const int wm = (wave >> 1) * 32, wn = (wave & 1) * 64;
  const int n0 = blockIdx.x * 128, m0 = blockIdx.y * 64;
  const int srow = tid >> 2, scol = (tid & 3) * 8;

  f32x4 acc[2][4] = {};

  const __bf16* aSrc = A  + (size_t)(m0 + srow) * Kdim + scol;
  const __bf16* bSrc = BT + (size_t)(n0 + srow) * Kdim + scol;

  auto stage = [&](int p, int k0) {
    __builtin_amdgcn_global_load_lds((glb_u32*)(aSrc + k0),              (lds_u32*)(As[p] + wave * 512),        16, 0, 0);
    __builtin_amdgcn_global_load_lds((glb_u32*)(bSrc + k0),              (lds_u32*)(Bs[p] + wave * 512),        16, 0, 0);
    __builtin_amdgcn_global_load_lds((glb_u32*)(bSrc + 64 * Kdim + k0), (lds_u32*)(Bs[p] + wave * 512 + 2048), 16, 0, 0);
  };

  const int nk = Kdim / 32;
  stage(0, 0);
  stage(1, 32);
  for (int kk = 0; kk < nk; ++kk) {
    const int cur = kk % 3;
    if (kk + 2 < nk) {
      stage((kk + 2) % 3, (kk + 2) * 32);
      asm volatile("s_waitcnt vmcnt(6)" ::: "memory");
    } else if (kk + 1 < nk) {
      asm volatile("s_waitcnt vmcnt(3)" ::: "memory");
    } else {
      asm volatile("s_waitcnt vmcnt(0)" ::: "memory");
    }
    __builtin_amdgcn_s_barrier();

    bf16x8 af[2], bfv[4];
#pragma unroll
    for (int i = 0; i < 2; ++i) af[i]  = *reinterpret_cast<const bf16x8*>(&As[cur][(wm + i * 16 + lr) * 32 + lg * 8]);
#pragma unroll
    for (int j = 0; j < 4; ++j) bfv[j] = *reinterpret_cast<const bf16x8*>(&Bs[cur][(wn + j * 16 + lr) * 32 + lg * 8]);
#pragma unroll
    for (int i = 0; i < 2; ++i)
#pragma unroll
      for (int j = 0; j < 4; ++j)
        acc[i][j] = __builtin_amdgcn_mfma_f32_16x16x32_bf16(af[i], bfv[j], acc[i][j], 0, 0, 0);

    asm volatile("s_waitcnt lgkmcnt(0)" ::: "memory");
    __builtin_amdgcn_s_barrier();
  }

#pragma unroll
  for (int i = 0; i < 2; ++i) {
#pragma unroll
    for (int j = 0; j < 4; ++j) {
      const int gc = n0 + wn + j * 16 + lr;
      const float bv = bias[gc];
#pragma unroll
      for (int ii = 0; ii < 4; ++ii) {
        const int gr = m0 + wm + i * 16 + lg * 4 + ii;
        fout[(size_t)gr * D_MODEL + gc] = acc[i][j][ii] + bv;
      }
    }
  }
}

// ---------------- causal flash attention: 4 waves/block, QBLK=64, V direct-from-L2 ----------------
// K staged in LDS (double-buffered, swizzled); V fragments loaded straight from global
// (VT [bh][d][s] makes each fragment a contiguous 16B load; issued before QK so latency
// hides under softmax+MFMA). Halves per-tile LDS traffic vs the staged-V version.
__global__ __launch_bounds__(256, 4) void attn_kernel(const __bf16* __restrict__ QT,
                                                      const __bf16* __restrict__ K,
                                                      const __bf16* __restrict__ VT,
                                                      __bf16* __restrict__ AO) {
  __shared__ __bf16 Kb[2][64 * 64];   // 8 KB each
  __shared__ __bf16 Ps[4][16 * 64];   // 8 KB -> total 24 KB

  const int tid  = threadIdx.x;
  const int lane = tid & 63, wave = tid >> 6;
  const int lr = lane & 15, lg = lane >> 4;

  const int f  = blockIdx.x;
  const int c  = f & 7;
  const int u  = f >> 3;
  const int bh = c * 4 + (u & 3);
  const int s2 = u >> 2, grp = s2 >> 3, r = s2 & 7;
  const int qblk = (grp == 0) ? (31 - r) : (grp == 1) ? r : (grp == 2) ? (39 - s2) : (s2 - 16);

  const int q0 = qblk * 64 + wave * 16;
  const size_t base = (size_t)bh * SEQ * HD;
  const char* Kg = (const char*)(K + base);

  // Q fragment from Qt[bh][d][s] (once per block)
  bf16x8 qf[2];
#pragma unroll
  for (int kc = 0; kc < 2; ++kc) {
    bf16x8 v;
#pragma unroll
    for (int j = 0; j < 8; ++j)
      v[j] = QT[base + (size_t)(kc * 32 + lg * 8 + j) * SEQ + q0 + lr];
    qf[kc] = v;
  }

  int pAddr[4][4];
#pragma unroll
  for (int n = 0; n < 4; ++n)
#pragma unroll
    for (int ii = 0; ii < 4; ++ii) {
      const int row = lg * 4 + ii;
      pAddr[n][ii] = row * 64 + (((n * 2 + (lr >> 3)) ^ (row & 7)) << 3) + (lr & 7);
    }

  float lrun[4] = {0.f, 0.f, 0.f, 0.f};
  f32x4 o[4] = {};

  const int nt = qblk + 1;
  const int nmaxF = (wave | 1) + 1;

  // stage K only: wave covers rows [wave*16, wave*16+16)
  auto stage = [&](int bufp, int t) {
    const int k0 = t * 64;
#pragma unroll
    for (int p = 0; p < 2; ++p) {
      const int row = wave * 16 + p * 8 + (lane >> 3);
      const int srcOff = (k0 + row) * 128 + (((lane & 7) ^ (row & 7)) << 4);
      __builtin_amdgcn_global_load_lds((glb_u32*)(Kg + srcOff),
                                       (lds_u32*)&Kb[bufp][(wave * 16 + p * 8) * 64], 16, 0, 0);
    }
  };

  stage(0, 0);
  asm volatile("s_waitcnt vmcnt(0)" ::: "memory");
  __syncthreads();

  for (int t = 0; t < nt; ++t) {
    const int p = t & 1;
    const int k0 = t * 64;
    const bool last = (t == nt - 1);
    const int nmax = last ? nmaxF : 4;
    const int kcmax = nmax >> 1;

    // ---- V fragments direct from global (issued first; latency hides under QK+softmax) ----
    bf16x8 vf[2][4];
#pragma unroll
    for (int kc = 0; kc < 2; ++kc)
      if (kc < kcmax)
#pragma unroll
        for (int nd = 0; nd < 4; ++nd)
          vf[kc][nd] = *reinterpret_cast<const bf16x8*>(
              VT + base + (size_t)(nd * 16 + lr) * SEQ + k0 + kc * 32 + lg * 8);

    // ---- prefetch next K tile ----
    if (t + 1 < nt) stage(p ^ 1, t + 1);

    const __bf16* Kt = Kb[p];

    f32x4 s[4] = {};
    __builtin_amdgcn_s_setprio(1);
#pragma unroll
    for (int kc = 0; kc < 2; ++kc) {
#pragma unroll
      for (int n = 0; n < 4; ++n)
        if (n < nmax) {
          bf16x8 kf = *reinterpret_cast<const bf16x8*>(
              &Kt[(n * 16 + lr) * 64 + (((kc * 4 + lg) ^ (lr & 7)) << 3)]);
          s[n] = __builtin_amdgcn_mfma_f32_16x16x32_bf16(qf[kc], kf, s[n], 0, 0, 0);
        }
    }
    __builtin_amdgcn_s_setprio(0);

    if (last) {
#pragma unroll
      for (int n = 0; n < 4; ++n)
        if (n < nmax)
#pragma unroll
          for (int ii = 0; ii < 4; ++ii) {
            int qg = q0 + lg * 4 + ii;
            int kg = k0 + n * 16 + lr;
            if (kg > qg) s[n][ii] = -__builtin_inff();
          }
    }

#pragma unroll
    for (int n = 0; n < 4; ++n)
      if (n < nmax)
#pragma unroll
        for (int ii = 0; ii < 4; ++ii) {
          float pv = __builtin_amdgcn_exp2f(s[n][ii]);
          lrun[ii] += pv;
          Ps[wave][pAddr[n][ii]] = (__bf16)pv;
        }

    __builtin_amdgcn_s_setprio(1);
#pragma unroll
    for (int kc = 0; kc < 2; ++kc)
      if (kc < kcmax) {
        bf16x8 pa = *reinterpret_cast<const bf16x8*>(
            &Ps[wave][lr * 64 + (((kc * 4 + lg) ^ (lr & 7)) << 3)]);
#pragma unroll
        for (int nd = 0; nd < 4; ++nd)
          o[nd] = __builtin_amdgcn_mfma_f32_16x16x32_bf16(pa, vf[kc][nd], o[nd], 0, 0, 0);
      }
    __builtin_amdgcn_s_setprio(0);

    asm volatile("s_waitcnt vmcnt(0)" ::: "memory");   // K(t+1) staged before next tile
    __syncthreads();
  }

#pragma unroll
  for (int off = 1; off <= 8; off <<= 1)
#pragma unroll
    for (int ii = 0; ii < 4; ++ii) lrun[ii] += __shfl_xor(lrun[ii], off, 64);

  const int b = bh >> 4, h = bh & 15;
  float rl[4];
#pragma unroll
  for (int ii = 0; ii < 4; ++ii) rl[ii] = 1.f / lrun[ii];
#pragma unroll
  for (int nd = 0; nd < 4; ++nd)
#pragma unroll
    for (int ii = 0; ii < 4; ++ii) {
      int row = q0 + lg * 4 + ii;
      AO[((size_t)(b * SEQ) + row) * D_MODEL + h * HD + nd * 16 + lr] = (__bf16)(o[nd][ii] * rl[ii]);
    }
}

// ---------------- launch ----------------
extern "C" void kernel_launch(void* const* d_in, const int* in_sizes, int n_in,
                              void* d_out, int out_size, void* d_ws, size_t ws_size,
                              hipStream_t stream) {
  const float* x      = (const float*)d_in[0];
  const float* w_qkv  = (const float*)d_in[1];
  const float* b_qkv  = (const float*)d_in[2];
  const float* w_proj = (const float*)d_in[3];
  const float* b_proj = (const float*)d_in[4];
  float* out = (float*)d_out;

  char* ws = (char*)d_ws;
  __bf16* xb     = (__bf16*)(ws);                    // 8 MiB
  __bf16* wqkvT  = (__bf16*)(ws + 8388608);          // 6 MiB
  __bf16* wprojT = (__bf16*)(ws + 14680064);         // 2 MiB
  __bf16* qtb    = (__bf16*)(ws + 16777216);         // 8 MiB (transposed Q)
  __bf16* kb     = (__bf16*)(ws + 25165824);         // 8 MiB
  __bf16* vtb    = (__bf16*)(ws + 33554432);         // 8 MiB (transposed V)
  __bf16* ao     = (__bf16*)(ws + 41943040);         // 8 MiB

  prep_kernel<<<5120, 256, 0, stream>>>(x, w_qkv, w_proj, xb, wqkvT, wprojT);

  gemm_qkv<<<768, 256, 0, stream>>>(xb, wqkvT, b_qkv, qtb, kb, vtb);

  attn_kernel<<<1024, 256, 0, stream>>>(qtb, kb, vtb, ao);

  gemm_proj<<<dim3(D_MODEL / 128, M_TOK / 64), 256, 0, stream>>>(
      ao, wprojT, b_proj, out);
}

// Round 24
// 105.383 us; speedup vs baseline: 1.2877x; 1.2869x over previous
//
#include <hip/hip_runtime.h>
#include <hip/hip_bf16.h>

#define D_MODEL 1024
#define SEQ     2048
#define NH      16
#define HD      64
#define M_TOK   4096
#define THREE_D 3072

using bf16x8 = __bf16 __attribute__((ext_vector_type(8)));
using bf16x4 = __bf16 __attribute__((ext_vector_type(4)));
using f32x4  = float  __attribute__((ext_vector_type(4)));

typedef __attribute__((address_space(3))) uint32_t lds_u32;
typedef const __attribute__((address_space(1))) uint32_t glb_u32;

// ---------------- fused prep: x cast (blocks 0..4095), w_qkv T (4096..4863), w_proj T (4864..5119) ----------------
__global__ __launch_bounds__(256) void prep_kernel(const float* __restrict__ x,
                                                   const float* __restrict__ w_qkv,
                                                   const float* __restrict__ w_proj,
                                                   __bf16* __restrict__ xb,
                                                   __bf16* __restrict__ wqkvT,
                                                   __bf16* __restrict__ wprojT) {
  const int bid = blockIdx.x;
  if (bid < 4096) {
    int i = bid * 256 + threadIdx.x;
    float4 f = reinterpret_cast<const float4*>(x)[i];
    bf16x4 o;
    o[0] = (__bf16)f.x; o[1] = (__bf16)f.y; o[2] = (__bf16)f.z; o[3] = (__bf16)f.w;
    reinterpret_cast<bf16x4*>(xb)[i] = o;
    return;
  }
  __shared__ float tile[64][65];
  const float* in; __bf16* out; int R, C, t;
  if (bid < 4864) { in = w_qkv;  out = wqkvT;  R = D_MODEL; C = THREE_D; t = bid - 4096; }
  else            { in = w_proj; out = wprojT; R = D_MODEL; C = D_MODEL; t = bid - 4864; }
  const int nCx = C / 64;
  const int c0 = (t % nCx) * 64, r0 = (t / nCx) * 64;
  const int tx = threadIdx.x & 63, ty = threadIdx.x >> 6;
#pragma unroll
  for (int i = 0; i < 16; ++i) {
    int r = ty + i * 4;
    tile[r][tx] = in[(size_t)(r0 + r) * C + c0 + tx];
  }
  __syncthreads();
#pragma unroll
  for (int i = 0; i < 16; ++i) {
    int r = ty + i * 4;
    out[(size_t)(c0 + r) * R + r0 + tx] = (__bf16)tile[tx][r];
  }
}

// ---------------- QKV GEMM: 128x128, BK=32, 3-deep pipeline (R20-exact) ----------------
// Q TRANSPOSED [bh][d][s] scaled 0.125*log2(e); K [bh][s][d]; V transposed [bh][d][s].
__global__ __launch_bounds__(256, 3) void gemm_qkv(const __bf16* __restrict__ A,
                                                   const __bf16* __restrict__ BT,
                                                   const float* __restrict__ bias,
                                                   __bf16* __restrict__ qt, __bf16* __restrict__ kb,
                                                   __bf16* __restrict__ vb) {
  __shared__ __bf16 As[3][128 * 32];
  __shared__ __bf16 Bs[3][128 * 32];
  const int Kdim = D_MODEL;
  const int tid  = threadIdx.x;
  const int lane = tid & 63, wave = tid >> 6;
  const int lr = lane & 15, lg = lane >> 4;
  const int wm = (wave >> 1) * 64, wn = (wave & 1) * 64;

  const int f   = blockIdx.x;
  const int swz = (f & 7) * 96 + (f >> 3);
  const int m0  = (swz / 24) * 128, n0 = (swz % 24) * 128;

  const int srow = tid >> 2, scol = (tid & 3) * 8;

  f32x4 acc[4][4] = {};

  const __bf16* aSrc = A  + (size_t)(m0 + srow) * Kdim + scol;
  const __bf16* bSrc = BT + (size_t)(n0 + srow) * Kdim + scol;

  auto stage = [&](int p, int k0) {
    __builtin_amdgcn_global_load_lds((glb_u32*)(aSrc + k0),              (lds_u32*)(As[p] + wave * 512),        16, 0, 0);
    __builtin_amdgcn_global_load_lds((glb_u32*)(aSrc + 64 * Kdim + k0), (lds_u32*)(As[p] + wave * 512 + 2048), 16, 0, 0);
    __builtin_amdgcn_global_load_lds((glb_u32*)(bSrc + k0),              (lds_u32*)(Bs[p] + wave * 512),        16, 0, 0);
    __builtin_amdgcn_global_load_lds((glb_u32*)(bSrc + 64 * Kdim + k0), (lds_u32*)(Bs[p] + wave * 512 + 2048), 16, 0, 0);
  };

  const int nk = Kdim / 32;
  stage(0, 0);
  stage(1, 32);
  for (int kk = 0; kk < nk; ++kk) {
    const int cur = kk % 3;
    if (kk + 2 < nk) {
      stage((kk + 2) % 3, (kk + 2) * 32);
      asm volatile("s_waitcnt vmcnt(8)" ::: "memory");
    } else if (kk + 1 < nk) {
      asm volatile("s_waitcnt vmcnt(4)" ::: "memory");
    } else {
      asm volatile("s_waitcnt vmcnt(0)" ::: "memory");
    }
    __builtin_amdgcn_s_barrier();

    bf16x8 af[4], bfv[4];
#pragma unroll
    for (int i = 0; i < 4; ++i) af[i]  = *reinterpret_cast<const bf16x8*>(&As[cur][(wm + i * 16 + lr) * 32 + lg * 8]);
#pragma unroll
    for (int j = 0; j < 4; ++j) bfv[j] = *reinterpret_cast<const bf16x8*>(&Bs[cur][(wn + j * 16 + lr) * 32 + lg * 8]);
#pragma unroll
    for (int i = 0; i < 4; ++i)
#pragma unroll
      for (int j = 0; j < 4; ++j)
        acc[i][j] = __builtin_amdgcn_mfma_f32_16x16x32_bf16(af[i], bfv[j], acc[i][j], 0, 0, 0);

    asm volatile("s_waitcnt lgkmcnt(0)" ::: "memory");
    __builtin_amdgcn_s_barrier();
  }

  const int reg = n0 >> 10;
  if (reg != 1) {
    __bf16* dst = (reg == 0) ? qt : vb;
    const float scl = (reg == 0) ? 0.18033688011112042f : 1.0f;   // 0.125*log2(e) for Q
#pragma unroll
    for (int j = 0; j < 4; ++j) {
      const int gc = n0 + wn + j * 16 + lr;
      const float bv = bias[gc];
      const int rem = gc & 1023, h = rem >> 6, d = rem & 63;
#pragma unroll
      for (int i = 0; i < 4; ++i) {
        const int gr0 = m0 + wm + i * 16 + lg * 4;
        const int b = gr0 >> 11, s0 = gr0 & 2047;
        bf16x4 v4;
#pragma unroll
        for (int ii = 0; ii < 4; ++ii) v4[ii] = (__bf16)((acc[i][j][ii] + bv) * scl);
        *reinterpret_cast<bf16x4*>(&dst[(((size_t)(b * NH + h)) * HD + d) * SEQ + s0]) = v4;
      }
    }
  } else {
#pragma unroll
    for (int i = 0; i < 4; ++i) {
#pragma unroll
      for (int j = 0; j < 4; ++j) {
        const int gc = n0 + wn + j * 16 + lr;
        const float bv = bias[gc];
        const int rem = gc & 1023, h = rem >> 6, d = rem & 63;
#pragma unroll
        for (int ii = 0; ii < 4; ++ii) {
          const int gr = m0 + wm + i * 16 + lg * 4 + ii;
          const int b = gr >> 11, s = gr & 2047;
          kb[(((size_t)(b * NH + h)) * SEQ + s) * HD + d] = (__bf16)(acc[i][j][ii] + bv);
        }
      }
    }
  }
}

// ---------------- proj GEMM: 64x128 tile, BK=32, 3-deep pipeline (R20-exact) ----------------
__global__ __launch_bounds__(256, 4) void gemm_proj(const __bf16* __restrict__ A,
                                                    const __bf16* __restrict__ BT,
                                                    const float* __restrict__ bias,
                                                    float* __restrict__ fout) {
  __shared__ __bf16 As[3][64 * 32];
  __shared__ __bf16 Bs[3][128 * 32];
  const int Kdim = D_MODEL;
  const int tid  = threadIdx.x;
  const int lane = tid & 63, wave = tid >> 6;
  const int lr = lane & 15, lg = lane >> 4;
  const int wm = (wave >> 1) * 32, wn = (wave & 1) * 64;
  const int n0 = blockIdx.x * 128, m0 = blockIdx.y * 64;
  const int srow = tid >> 2, scol = (tid & 3) * 8;

  f32x4 acc[2][4] = {};

  const __bf16* aSrc = A  + (size_t)(m0 + srow) * Kdim + scol;
  const __bf16* bSrc = BT + (size_t)(n0 + srow) * Kdim + scol;

  auto stage = [&](int p, int k0) {
    __builtin_amdgcn_global_load_lds((glb_u32*)(aSrc + k0),              (lds_u32*)(As[p] + wave * 512),        16, 0, 0);
    __builtin_amdgcn_global_load_lds((glb_u32*)(bSrc + k0),              (lds_u32*)(Bs[p] + wave * 512),        16, 0, 0);
    __builtin_amdgcn_global_load_lds((glb_u32*)(bSrc + 64 * Kdim + k0), (lds_u32*)(Bs[p] + wave * 512 + 2048), 16, 0, 0);
  };

  const int nk = Kdim / 32;
  stage(0, 0);
  stage(1, 32);
  for (int kk = 0; kk < nk; ++kk) {
    const int cur = kk % 3;
    if (kk + 2 < nk) {
      stage((kk + 2) % 3, (kk + 2) * 32);
      asm volatile("s_waitcnt vmcnt(6)" ::: "memory");
    } else if (kk + 1 < nk) {
      asm volatile("s_waitcnt vmcnt(3)" ::: "memory");
    } else {
      asm volatile("s_waitcnt vmcnt(0)" ::: "memory");
    }
    __builtin_amdgcn_s_barrier();

    bf16x8 af[2], bfv[4];
#pragma unroll
    for (int i = 0; i < 2; ++i) af[i]  = *reinterpret_cast<const bf16x8*>(&As[cur][(wm + i * 16 + lr) * 32 + lg * 8]);
#pragma unroll
    for (int j = 0; j < 4; ++j) bfv[j] = *reinterpret_cast<const bf16x8*>(&Bs[cur][(wn + j * 16 + lr) * 32 + lg * 8]);
#pragma unroll
    for (int i = 0; i < 2; ++i)
#pragma unroll
      for (int j = 0; j < 4; ++j)
        acc[i][j] = __builtin_amdgcn_mfma_f32_16x16x32_bf16(af[i], bfv[j], acc[i][j], 0, 0, 0);

    asm volatile("s_waitcnt lgkmcnt(0)" ::: "memory");
    __builtin_amdgcn_s_barrier();
  }

#pragma unroll
  for (int i = 0; i < 2; ++i) {
#pragma unroll
    for (int j = 0; j < 4; ++j) {
      const int gc = n0 + wn + j * 16 + lr;
      const float bv = bias[gc];
#pragma unroll
      for (int ii = 0; ii < 4; ++ii) {
        const int gr = m0 + wm + i * 16 + lg * 4 + ii;
        fout[(size_t)gr * D_MODEL + gc] = acc[i][j][ii] + bv;
      }
    }
  }
}

// ---------------- causal flash attention: 4 waves/block, QBLK=64 (R20-exact) ----------------
__global__ __launch_bounds__(256, 4) void attn_kernel(const __bf16* __restrict__ QT,
                                                      const __bf16* __restrict__ K,
                                                      const __bf16* __restrict__ VT,
                                                      __bf16* __restrict__ AO) {
  __shared__ __bf16 Kb[2][64 * 64];
  __shared__ __bf16 Vb[2][64 * 64];
  __shared__ __bf16 Ps[4][16 * 64];

  const int tid  = threadIdx.x;
  const int lane = tid & 63, wave = tid >> 6;
  const int lr = lane & 15, lg = lane >> 4;

  const int f  = blockIdx.x;
  const int c  = f & 7;
  const int u  = f >> 3;
  const int bh = c * 4 + (u & 3);
  const int s2 = u >> 2, grp = s2 >> 3, r = s2 & 7;
  const int qblk = (grp == 0) ? (31 - r) : (grp == 1) ? r : (grp == 2) ? (39 - s2) : (s2 - 16);

  const int q0 = qblk * 64 + wave * 16;
  const size_t base = (size_t)bh * SEQ * HD;
  const char* Kg  = (const char*)(K + base);
  const char* VTg = (const char*)(VT + base);

  bf16x8 qf[2];
#pragma unroll
  for (int kc = 0; kc < 2; ++kc) {
    bf16x8 v;
#pragma unroll
    for (int j = 0; j < 8; ++j)
      v[j] = QT[base + (size_t)(kc * 32 + lg * 8 + j) * SEQ + q0 + lr];
    qf[kc] = v;
  }

  int pAddr[4][4];
#pragma unroll
  for (int n = 0; n < 4; ++n)
#pragma unroll
    for (int ii = 0; ii < 4; ++ii) {
      const int row = lg * 4 + ii;
      pAddr[n][ii] = row * 64 + (((n * 2 + (lr >> 3)) ^ (row & 7)) << 3) + (lr & 7);
    }

  float lrun[4] = {0.f, 0.f, 0.f, 0.f};
  f32x4 o[4] = {};

  const int nt = qblk + 1;
  const int nmaxF = (wave | 1) + 1;

  auto stage = [&](int bufp, int t) {
    const int k0 = t * 64;
#pragma unroll
    for (int p = 0; p < 2; ++p) {
      const int row = wave * 16 + p * 8 + (lane >> 3);
      {
        const int srcOff = (k0 + row) * 128 + (((lane & 7) ^ (row & 7)) << 4);
        __builtin_amdgcn_global_load_lds((glb_u32*)(Kg + srcOff),
                                         (lds_u32*)&Kb[bufp][(wave * 16 + p * 8) * 64], 16, 0, 0);
      }
      {
        const int srcOff = row * 4096 + k0 * 2 + (((lane & 7) ^ (row & 7)) << 4);
        __builtin_amdgcn_global_load_lds((glb_u32*)(VTg + srcOff),
                                         (lds_u32*)&Vb[bufp][(wave * 16 + p * 8) * 64], 16, 0, 0);
      }
    }
  };

  stage(0, 0);
  asm volatile("s_waitcnt vmcnt(0)" ::: "memory");
  __syncthreads();

  for (int t = 0; t < nt; ++t) {
    const int p = t & 1;
    const int k0 = t * 64;
    const bool last = (t == nt - 1);
    const int nmax = last ? nmaxF : 4;
    const int kcmax = nmax >> 1;

    if (t + 1 < nt) stage(p ^ 1, t + 1);

    const __bf16* Kt = Kb[p];
    const __bf16* Vt = Vb[p];

    f32x4 s[4] = {};
    __builtin_amdgcn_s_setprio(1);
#pragma unroll
    for (int kc = 0; kc < 2; ++kc) {
#pragma unroll
      for (int n = 0; n < 4; ++n)
        if (n < nmax) {
          bf16x8 kf = *reinterpret_cast<const bf16x8*>(
              &Kt[(n * 16 + lr) * 64 + (((kc * 4 + lg) ^ (lr & 7)) << 3)]);
          s[n] = __builtin_amdgcn_mfma_f32_16x16x32_bf16(qf[kc], kf, s[n], 0, 0, 0);
        }
    }
    __builtin_amdgcn_s_setprio(0);

    if (last) {
#pragma unroll
      for (int n = 0; n < 4; ++n)
        if (n < nmax)
#pragma unroll
          for (int ii = 0; ii < 4; ++ii) {
            int qg = q0 + lg * 4 + ii;
            int kg = k0 + n * 16 + lr;
            if (kg > qg) s[n][ii] = -__builtin_inff();
          }
    }

#pragma unroll
    for (int n = 0; n < 4; ++n)
      if (n < nmax)
#pragma unroll
        for (int ii = 0; ii < 4; ++ii) {
          float pv = __builtin_amdgcn_exp2f(s[n][ii]);
          lrun[ii] += pv;
          Ps[wave][pAddr[n][ii]] = (__bf16)pv;
        }

    __builtin_amdgcn_s_setprio(1);
#pragma unroll
    for (int kc = 0; kc < 2; ++kc)
      if (kc < kcmax) {
        bf16x8 pa = *reinterpret_cast<const bf16x8*>(
            &Ps[wave][lr * 64 + (((kc * 4 + lg) ^ (lr & 7)) << 3)]);
#pragma unroll
        for (int nd = 0; nd < 4; ++nd) {
          bf16x8 vf = *reinterpret_cast<const bf16x8*>(
              &Vt[(nd * 16 + lr) * 64 + (((kc * 4 + lg) ^ (lr & 7)) << 3)]);
          o[nd] = __builtin_amdgcn_mfma_f32_16x16x32_bf16(pa, vf, o[nd], 0, 0, 0);
        }
      }
    __builtin_amdgcn_s_setprio(0);

    asm volatile("s_waitcnt vmcnt(0)" ::: "memory");
    __syncthreads();
  }

#pragma unroll
  for (int off = 1; off <= 8; off <<= 1)
#pragma unroll
    for (int ii = 0; ii < 4; ++ii) lrun[ii] += __shfl_xor(lrun[ii], off, 64);

  const int b = bh >> 4, h = bh & 15;
  float rl[4];
#pragma unroll
  for (int ii = 0; ii < 4; ++ii) rl[ii] = 1.f / lrun[ii];
#pragma unroll
  for (int nd = 0; nd < 4; ++nd)
#pragma unroll
    for (int ii = 0; ii < 4; ++ii) {
      int row = q0 + lg * 4 + ii;
      AO[((size_t)(b * SEQ) + row) * D_MODEL + h * HD + nd * 16 + lr] = (__bf16)(o[nd][ii] * rl[ii]);
    }
}

// ---------------- launch ----------------
extern "C" void kernel_launch(void* const* d_in, const int* in_sizes, int n_in,
                              void* d_out, int out_size, void* d_ws, size_t ws_size,
                              hipStream_t stream) {
  const float* x      = (const float*)d_in[0];
  const float* w_qkv  = (const float*)d_in[1];
  const float* b_qkv  = (const float*)d_in[2];
  const float* w_proj = (const float*)d_in[3];
  const float* b_proj = (const float*)d_in[4];
  float* out = (float*)d_out;

  char* ws = (char*)d_ws;
  __bf16* xb     = (__bf16*)(ws);                    // 8 MiB
  __bf16* wqkvT  = (__bf16*)(ws + 8388608);          // 6 MiB
  __bf16* wprojT = (__bf16*)(ws + 14680064);         // 2 MiB
  __bf16* qtb    = (__bf16*)(ws + 16777216);         // 8 MiB (transposed Q)
  __bf16* kb     = (__bf16*)(ws + 25165824);         // 8 MiB
  __bf16* vtb    = (__bf16*)(ws + 33554432);         // 8 MiB (transposed V)
  __bf16* ao     = (__bf16*)(ws + 41943040);         // 8 MiB

  prep_kernel<<<5120, 256, 0, stream>>>(x, w_qkv, w_proj, xb, wqkvT, wprojT);

  gemm_qkv<<<768, 256, 0, stream>>>(xb, wqkvT, b_qkv, qtb, kb, vtb);

  attn_kernel<<<1024, 256, 0, stream>>>(qtb, kb, vtb, ao);

  gemm_proj<<<dim3(D_MODEL / 128, M_TOK / 64), 256, 0, stream>>>(
      ao, wprojT, b_proj, out);
}

// Round 25
// 102.941 us; speedup vs baseline: 1.3183x; 1.0237x over previous
//
#include <hip/hip_runtime.h>
#include <hip/hip_bf16.h>

#define D_MODEL 1024
#define SEQ     2048
#define NH      16
#define HD      64
#define M_TOK   4096
#define THREE_D 3072

using bf16x8 = __bf16 __attribute__((ext_vector_type(8)));
using bf16x4 = __bf16 __attribute__((ext_vector_type(4)));
using f32x4  = float  __attribute__((ext_vector_type(4)));

typedef __attribute__((address_space(3))) uint32_t lds_u32;
typedef const __attribute__((address_space(1))) uint32_t glb_u32;

// ---------------- fused prep: x cast (blocks 0..4095), w_qkv T (4096..4863), w_proj T (4864..5119) ----------------
__global__ __launch_bounds__(256) void prep_kernel(const float* __restrict__ x,
                                                   const float* __restrict__ w_qkv,
                                                   const float* __restrict__ w_proj,
                                                   __bf16* __restrict__ xb,
                                                   __bf16* __restrict__ wqkvT,
                                                   __bf16* __restrict__ wprojT) {
  const int bid = blockIdx.x;
  if (bid < 4096) {
    int i = bid * 256 + threadIdx.x;
    float4 f = reinterpret_cast<const float4*>(x)[i];
    bf16x4 o;
    o[0] = (__bf16)f.x; o[1] = (__bf16)f.y; o[2] = (__bf16)f.z; o[3] = (__bf16)f.w;
    reinterpret_cast<bf16x4*>(xb)[i] = o;
    return;
  }
  __shared__ float tile[64][65];
  const float* in; __bf16* out; int R, C, t;
  if (bid < 4864) { in = w_qkv;  out = wqkvT;  R = D_MODEL; C = THREE_D; t = bid - 4096; }
  else            { in = w_proj; out = wprojT; R = D_MODEL; C = D_MODEL; t = bid - 4864; }
  const int nCx = C / 64;
  const int c0 = (t % nCx) * 64, r0 = (t / nCx) * 64;
  const int tx = threadIdx.x & 63, ty = threadIdx.x >> 6;
#pragma unroll
  for (int i = 0; i < 16; ++i) {
    int r = ty + i * 4;
    tile[r][tx] = in[(size_t)(r0 + r) * C + c0 + tx];
  }
  __syncthreads();
#pragma unroll
  for (int i = 0; i < 16; ++i) {
    int r = ty + i * 4;
    out[(size_t)(c0 + r) * R + r0 + tx] = (__bf16)tile[tx][r];
  }
}

// ---------------- QKV GEMM: 128x128, BK=32, 3-deep pipeline (R20-exact) ----------------
// Q TRANSPOSED [bh][d][s] scaled 0.125*log2(e); K [bh][s][d]; V transposed [bh][d][s].
__global__ __launch_bounds__(256, 3) void gemm_qkv(const __bf16* __restrict__ A,
                                                   const __bf16* __restrict__ BT,
                                                   const float* __restrict__ bias,
                                                   __bf16* __restrict__ qt, __bf16* __restrict__ kb,
                                                   __bf16* __restrict__ vb) {
  __shared__ __bf16 As[3][128 * 32];
  __shared__ __bf16 Bs[3][128 * 32];
  const int Kdim = D_MODEL;
  const int tid  = threadIdx.x;
  const int lane = tid & 63, wave = tid >> 6;
  const int lr = lane & 15, lg = lane >> 4;
  const int wm = (wave >> 1) * 64, wn = (wave & 1) * 64;

  const int f   = blockIdx.x;
  const int swz = (f & 7) * 96 + (f >> 3);
  const int m0  = (swz / 24) * 128, n0 = (swz % 24) * 128;

  const int srow = tid >> 2, scol = (tid & 3) * 8;

  f32x4 acc[4][4] = {};

  const __bf16* aSrc = A  + (size_t)(m0 + srow) * Kdim + scol;
  const __bf16* bSrc = BT + (size_t)(n0 + srow) * Kdim + scol;

  auto stage = [&](int p, int k0) {
    __builtin_amdgcn_global_load_lds((glb_u32*)(aSrc + k0),              (lds_u32*)(As[p] + wave * 512),        16, 0, 0);
    __builtin_amdgcn_global_load_lds((glb_u32*)(aSrc + 64 * Kdim + k0), (lds_u32*)(As[p] + wave * 512 + 2048), 16, 0, 0);
    __builtin_amdgcn_global_load_lds((glb_u32*)(bSrc + k0),              (lds_u32*)(Bs[p] + wave * 512),        16, 0, 0);
    __builtin_amdgcn_global_load_lds((glb_u32*)(bSrc + 64 * Kdim + k0), (lds_u32*)(Bs[p] + wave * 512 + 2048), 16, 0, 0);
  };

  const int nk = Kdim / 32;
  stage(0, 0);
  stage(1, 32);
  for (int kk = 0; kk < nk; ++kk) {
    const int cur = kk % 3;
    if (kk + 2 < nk) {
      stage((kk + 2) % 3, (kk + 2) * 32);
      asm volatile("s_waitcnt vmcnt(8)" ::: "memory");
    } else if (kk + 1 < nk) {
      asm volatile("s_waitcnt vmcnt(4)" ::: "memory");
    } else {
      asm volatile("s_waitcnt vmcnt(0)" ::: "memory");
    }
    __builtin_amdgcn_s_barrier();

    bf16x8 af[4], bfv[4];
#pragma unroll
    for (int i = 0; i < 4; ++i) af[i]  = *reinterpret_cast<const bf16x8*>(&As[cur][(wm + i * 16 + lr) * 32 + lg * 8]);
#pragma unroll
    for (int j = 0; j < 4; ++j) bfv[j] = *reinterpret_cast<const bf16x8*>(&Bs[cur][(wn + j * 16 + lr) * 32 + lg * 8]);
#pragma unroll
    for (int i = 0; i < 4; ++i)
#pragma unroll
      for (int j = 0; j < 4; ++j)
        acc[i][j] = __builtin_amdgcn_mfma_f32_16x16x32_bf16(af[i], bfv[j], acc[i][j], 0, 0, 0);

    asm volatile("s_waitcnt lgkmcnt(0)" ::: "memory");
    __builtin_amdgcn_s_barrier();
  }

  const int reg = n0 >> 10;
  if (reg != 1) {
    __bf16* dst = (reg == 0) ? qt : vb;
    const float scl = (reg == 0) ? 0.18033688011112042f : 1.0f;   // 0.125*log2(e) for Q
#pragma unroll
    for (int j = 0; j < 4; ++j) {
      const int gc = n0 + wn + j * 16 + lr;
      const float bv = bias[gc];
      const int rem = gc & 1023, h = rem >> 6, d = rem & 63;
#pragma unroll
      for (int i = 0; i < 4; ++i) {
        const int gr0 = m0 + wm + i * 16 + lg * 4;
        const int b = gr0 >> 11, s0 = gr0 & 2047;
        bf16x4 v4;
#pragma unroll
        for (int ii = 0; ii < 4; ++ii) v4[ii] = (__bf16)((acc[i][j][ii] + bv) * scl);
        *reinterpret_cast<bf16x4*>(&dst[(((size_t)(b * NH + h)) * HD + d) * SEQ + s0]) = v4;
      }
    }
  } else {
#pragma unroll
    for (int i = 0; i < 4; ++i) {
#pragma unroll
      for (int j = 0; j < 4; ++j) {
        const int gc = n0 + wn + j * 16 + lr;
        const float bv = bias[gc];
        const int rem = gc & 1023, h = rem >> 6, d = rem & 63;
#pragma unroll
        for (int ii = 0; ii < 4; ++ii) {
          const int gr = m0 + wm + i * 16 + lg * 4 + ii;
          const int b = gr >> 11, s = gr & 2047;
          kb[(((size_t)(b * NH + h)) * SEQ + s) * HD + d] = (__bf16)(acc[i][j][ii] + bv);
        }
      }
    }
  }
}

// ---------------- proj GEMM: 64x128 tile, BK=32, 3-deep pipeline (R20-exact) ----------------
__global__ __launch_bounds__(256, 4) void gemm_proj(const __bf16* __restrict__ A,
                                                    const __bf16* __restrict__ BT,
                                                    const float* __restrict__ bias,
                                                    float* __restrict__ fout) {
  __shared__ __bf16 As[3][64 * 32];
  __shared__ __bf16 Bs[3][128 * 32];
  const int Kdim = D_MODEL;
  const int tid  = threadIdx.x;
  const int lane = tid & 63, wave = tid >> 6;
  const int lr = lane & 15, lg = lane >> 4;
  const int wm = (wave >> 1) * 32, wn = (wave & 1) * 64;
  const int n0 = blockIdx.x * 128, m0 = blockIdx.y * 64;
  const int srow = tid >> 2, scol = (tid & 3) * 8;

  f32x4 acc[2][4] = {};

  const __bf16* aSrc = A  + (size_t)(m0 + srow) * Kdim + scol;
  const __bf16* bSrc = BT + (size_t)(n0 + srow) * Kdim + scol;

  auto stage = [&](int p, int k0) {
    __builtin_amdgcn_global_load_lds((glb_u32*)(aSrc + k0),              (lds_u32*)(As[p] + wave * 512),        16, 0, 0);
    __builtin_amdgcn_global_load_lds((glb_u32*)(bSrc + k0),              (lds_u32*)(Bs[p] + wave * 512),        16, 0, 0);
    __builtin_amdgcn_global_load_lds((glb_u32*)(bSrc + 64 * Kdim + k0), (lds_u32*)(Bs[p] + wave * 512 + 2048), 16, 0, 0);
  };

  const int nk = Kdim / 32;
  stage(0, 0);
  stage(1, 32);
  for (int kk = 0; kk < nk; ++kk) {
    const int cur = kk % 3;
    if (kk + 2 < nk) {
      stage((kk + 2) % 3, (kk + 2) * 32);
      asm volatile("s_waitcnt vmcnt(6)" ::: "memory");
    } else if (kk + 1 < nk) {
      asm volatile("s_waitcnt vmcnt(3)" ::: "memory");
    } else {
      asm volatile("s_waitcnt vmcnt(0)" ::: "memory");
    }
    __builtin_amdgcn_s_barrier();

    bf16x8 af[2], bfv[4];
#pragma unroll
    for (int i = 0; i < 2; ++i) af[i]  = *reinterpret_cast<const bf16x8*>(&As[cur][(wm + i * 16 + lr) * 32 + lg * 8]);
#pragma unroll
    for (int j = 0; j < 4; ++j) bfv[j] = *reinterpret_cast<const bf16x8*>(&Bs[cur][(wn + j * 16 + lr) * 32 + lg * 8]);
#pragma unroll
    for (int i = 0; i < 2; ++i)
#pragma unroll
      for (int j = 0; j < 4; ++j)
        acc[i][j] = __builtin_amdgcn_mfma_f32_16x16x32_bf16(af[i], bfv[j], acc[i][j], 0, 0, 0);

    asm volatile("s_waitcnt lgkmcnt(0)" ::: "memory");
    __builtin_amdgcn_s_barrier();
  }

#pragma unroll
  for (int i = 0; i < 2; ++i) {
#pragma unroll
    for (int j = 0; j < 4; ++j) {
      const int gc = n0 + wn + j * 16 + lr;
      const float bv = bias[gc];
#pragma unroll
      for (int ii = 0; ii < 4; ++ii) {
        const int gr = m0 + wm + i * 16 + lg * 4 + ii;
        fout[(size_t)gr * D_MODEL + gc] = acc[i][j][ii] + bv;
      }
    }
  }
}

// ---------------- causal flash attention: 4 waves/block, QBLK=64, SWAPPED QK^T ----------------
// mfma(kf, qf) computes S^T: lane (lr,lg) holds S[q=lr][k=n*16+lg*4+ii] -> 4 consecutive
// keys per n => packed bf16x4 P-stores (4 ds_write_b64 vs 16 ds_write_b16), per-lane scalar
// row-sum (+2 shuffles once). PV read side and all staging identical to R20.
__global__ __launch_bounds__(256, 4) void attn_kernel(const __bf16* __restrict__ QT,
                                                      const __bf16* __restrict__ K,
                                                      const __bf16* __restrict__ VT,
                                                      __bf16* __restrict__ AO) {
  __shared__ __bf16 Kb[2][64 * 64];
  __shared__ __bf16 Vb[2][64 * 64];
  __shared__ __bf16 Ps[4][16 * 64];

  const int tid  = threadIdx.x;
  const int lane = tid & 63, wave = tid >> 6;
  const int lr = lane & 15, lg = lane >> 4;

  const int f  = blockIdx.x;
  const int c  = f & 7;
  const int u  = f >> 3;
  const int bh = c * 4 + (u & 3);
  const int s2 = u >> 2, grp = s2 >> 3, r = s2 & 7;
  const int qblk = (grp == 0) ? (31 - r) : (grp == 1) ? r : (grp == 2) ? (39 - s2) : (s2 - 16);

  const int q0 = qblk * 64 + wave * 16;
  const size_t base = (size_t)bh * SEQ * HD;
  const char* Kg  = (const char*)(K + base);
  const char* VTg = (const char*)(VT + base);

  // Q fragment from Qt[bh][d][s] (once per block); same registers serve as the
  // B-operand of the swapped QK^T (A/B fragments share the lane mapping).
  bf16x8 qf[2];
#pragma unroll
  for (int kc = 0; kc < 2; ++kc) {
    bf16x8 v;
#pragma unroll
    for (int j = 0; j < 8; ++j)
      v[j] = QT[base + (size_t)(kc * 32 + lg * 8 + j) * SEQ + q0 + lr];
    qf[kc] = v;
  }

  // loop-invariant packed P-write offsets: row=lr, keys n*16+lg*4..+3
  // element = n*16+lg*4 -> chunk = n*2+(lg>>1), swizzled by lr&7; in-chunk off (lg&1)*4
  int pWr[4];
#pragma unroll
  for (int n = 0; n < 4; ++n)
    pWr[n] = lr * 64 + (((n * 2 + (lg >> 1)) ^ (lr & 7)) << 3) + (lg & 1) * 4;

  float lsum = 0.f;
  f32x4 o[4] = {};

  const int nt = qblk + 1;
  const int nmaxF = (wave | 1) + 1;

  auto stage = [&](int bufp, int t) {
    const int k0 = t * 64;
#pragma unroll
    for (int p = 0; p < 2; ++p) {
      const int row = wave * 16 + p * 8 + (lane >> 3);
      {
        const int srcOff = (k0 + row) * 128 + (((lane & 7) ^ (row & 7)) << 4);
        __builtin_amdgcn_global_load_lds((glb_u32*)(Kg + srcOff),
                                         (lds_u32*)&Kb[bufp][(wave * 16 + p * 8) * 64], 16, 0, 0);
      }
      {
        const int srcOff = row * 4096 + k0 * 2 + (((lane & 7) ^ (row & 7)) << 4);
        __builtin_amdgcn_global_load_lds((glb_u32*)(VTg + srcOff),
                                         (lds_u32*)&Vb[bufp][(wave * 16 + p * 8) * 64], 16, 0, 0);
      }
    }
  };

  stage(0, 0);
  asm volatile("s_waitcnt vmcnt(0)" ::: "memory");
  __syncthreads();

  for (int t = 0; t < nt; ++t) {
    const int p = t & 1;
    const int k0 = t * 64;
    const bool last = (t == nt - 1);
    const int nmax = last ? nmaxF : 4;
    const int kcmax = nmax >> 1;

    if (t + 1 < nt) stage(p ^ 1, t + 1);

    const __bf16* Kt = Kb[p];
    const __bf16* Vt = Vb[p];

    // ---- swapped QK^T: s[n][ii] = S[q0+lr][k0 + n*16 + lg*4 + ii] ----
    f32x4 s[4] = {};
    __builtin_amdgcn_s_setprio(1);
#pragma unroll
    for (int kc = 0; kc < 2; ++kc) {
#pragma unroll
      for (int n = 0; n < 4; ++n)
        if (n < nmax) {
          bf16x8 kf = *reinterpret_cast<const bf16x8*>(
              &Kt[(n * 16 + lr) * 64 + (((kc * 4 + lg) ^ (lr & 7)) << 3)]);
          s[n] = __builtin_amdgcn_mfma_f32_16x16x32_bf16(kf, qf[kc], s[n], 0, 0, 0);
        }
    }
    __builtin_amdgcn_s_setprio(0);

    if (last) {  // causal mask: qg = q0+lr, kg = k0 + n*16 + lg*4 + ii
      const int qg = q0 + lr;
#pragma unroll
      for (int n = 0; n < 4; ++n)
        if (n < nmax)
#pragma unroll
          for (int ii = 0; ii < 4; ++ii) {
            int kg = k0 + n * 16 + lg * 4 + ii;
            if (kg > qg) s[n][ii] = -__builtin_inff();
          }
    }

    // ---- exp + packed P store (one ds_write_b64 per n) + per-lane row-sum ----
#pragma unroll
    for (int n = 0; n < 4; ++n)
      if (n < nmax) {
        bf16x4 pv4;
#pragma unroll
        for (int ii = 0; ii < 4; ++ii) {
          float pv = __builtin_amdgcn_exp2f(s[n][ii]);   // Q carries log2(e); exp2(-inf)=0
          lsum += pv;
          pv4[ii] = (__bf16)pv;
        }
        *reinterpret_cast<bf16x4*>(&Ps[wave][pWr[n]]) = pv4;
      }

    // ---- PV (read side unchanged) ----
    __builtin_amdgcn_s_setprio(1);
#pragma unroll
    for (int kc = 0; kc < 2; ++kc)
      if (kc < kcmax) {
        bf16x8 pa = *reinterpret_cast<const bf16x8*>(
            &Ps[wave][lr * 64 + (((kc * 4 + lg) ^ (lr & 7)) << 3)]);
#pragma unroll
        for (int nd = 0; nd < 4; ++nd) {
          bf16x8 vf = *reinterpret_cast<const bf16x8*>(
              &Vt[(nd * 16 + lr) * 64 + (((kc * 4 + lg) ^ (lr & 7)) << 3)]);
          o[nd] = __builtin_amdgcn_mfma_f32_16x16x32_bf16(pa, vf, o[nd], 0, 0, 0);
        }
      }
    __builtin_amdgcn_s_setprio(0);

    asm volatile("s_waitcnt vmcnt(0)" ::: "memory");
    __syncthreads();
  }

  // ---- row-sum: combine the 4 lg-copies of q=lr (lanes lr, lr+16, lr+32, lr+48) ----
  lsum += __shfl_xor(lsum, 16, 64);
  lsum += __shfl_xor(lsum, 32, 64);

  const int b = bh >> 4, h = bh & 15;
  float rl[4];
#pragma unroll
  for (int ii = 0; ii < 4; ++ii)
    rl[ii] = 1.f / __shfl(lsum, lg * 4 + ii, 64);   // sum for q-row lg*4+ii lives at lane lr=lg*4+ii

#pragma unroll
  for (int nd = 0; nd < 4; ++nd)
#pragma unroll
    for (int ii = 0; ii < 4; ++ii) {
      int row = q0 + lg * 4 + ii;
      AO[((size_t)(b * SEQ) + row) * D_MODEL + h * HD + nd * 16 + lr] = (__bf16)(o[nd][ii] * rl[ii]);
    }
}

// ---------------- launch ----------------
extern "C" void kernel_launch(void* const* d_in, const int* in_sizes, int n_in,
                              void* d_out, int out_size, void* d_ws, size_t ws_size,
                              hipStream_t stream) {
  const float* x      = (const float*)d_in[0];
  const float* w_qkv  = (const float*)d_in[1];
  const float* b_qkv  = (const float*)d_in[2];
  const float* w_proj = (const float*)d_in[3];
  const float* b_proj = (const float*)d_in[4];
  float* out = (float*)d_out;

  char* ws = (char*)d_ws;
  __bf16* xb     = (__bf16*)(ws);                    // 8 MiB
  __bf16* wqkvT  = (__bf16*)(ws + 8388608);          // 6 MiB
  __bf16* wprojT = (__bf16*)(ws + 14680064);         // 2 MiB
  __bf16* qtb    = (__bf16*)(ws + 16777216);         // 8 MiB (transposed Q)
  __bf16* kb     = (__bf16*)(ws + 25165824);         // 8 MiB
  __bf16* vtb    = (__bf16*)(ws + 33554432);         // 8 MiB (transposed V)
  __bf16* ao     = (__bf16*)(ws + 41943040);         // 8 MiB

  prep_kernel<<<5120, 256, 0, stream>>>(x, w_qkv, w_proj, xb, wqkvT, wprojT);

  gemm_qkv<<<768, 256, 0, stream>>>(xb, wqkvT, b_qkv, qtb, kb, vtb);

  attn_kernel<<<1024, 256, 0, stream>>>(qtb, kb, vtb, ao);

  gemm_proj<<<dim3(D_MODEL / 128, M_TOK / 64), 256, 0, stream>>>(
      ao, wprojT, b_proj, out);
}

// Round 26
// 102.608 us; speedup vs baseline: 1.3225x; 1.0032x over previous
//
#include <hip/hip_runtime.h>
#include <hip/hip_bf16.h>

#define D_MODEL 1024
#define SEQ     2048
#define NH      16
#define HD      64
#define M_TOK   4096
#define THREE_D 3072

using bf16x8 = __bf16 __attribute__((ext_vector_type(8)));
using bf16x4 = __bf16 __attribute__((ext_vector_type(4)));
using f32x4  = float  __attribute__((ext_vector_type(4)));

typedef __attribute__((address_space(3))) uint32_t lds_u32;
typedef const __attribute__((address_space(1))) uint32_t glb_u32;

// ---------------- fused prep: x cast (blocks 0..4095), w_qkv T (4096..4863), w_proj T (4864..5119) ----------------
__global__ __launch_bounds__(256) void prep_kernel(const float* __restrict__ x,
                                                   const float* __restrict__ w_qkv,
                                                   const float* __restrict__ w_proj,
                                                   __bf16* __restrict__ xb,
                                                   __bf16* __restrict__ wqkvT,
                                                   __bf16* __restrict__ wprojT) {
  const int bid = blockIdx.x;
  if (bid < 4096) {
    int i = bid * 256 + threadIdx.x;
    float4 f = reinterpret_cast<const float4*>(x)[i];
    bf16x4 o;
    o[0] = (__bf16)f.x; o[1] = (__bf16)f.y; o[2] = (__bf16)f.z; o[3] = (__bf16)f.w;
    reinterpret_cast<bf16x4*>(xb)[i] = o;
    return;
  }
  __shared__ float tile[64][65];
  const float* in; __bf16* out; int R, C, t;
  if (bid < 4864) { in = w_qkv;  out = wqkvT;  R = D_MODEL; C = THREE_D; t = bid - 4096; }
  else            { in = w_proj; out = wprojT; R = D_MODEL; C = D_MODEL; t = bid - 4864; }
  const int nCx = C / 64;
  const int c0 = (t % nCx) * 64, r0 = (t / nCx) * 64;
  const int tx = threadIdx.x & 63, ty = threadIdx.x >> 6;
#pragma unroll
  for (int i = 0; i < 16; ++i) {
    int r = ty + i * 4;
    tile[r][tx] = in[(size_t)(r0 + r) * C + c0 + tx];
  }
  __syncthreads();
#pragma unroll
  for (int i = 0; i < 16; ++i) {
    int r = ty + i * 4;
    out[(size_t)(c0 + r) * R + r0 + tx] = (__bf16)tile[tx][r];
  }
}

// ---------------- QKV GEMM: 128x128, BK=32, 3-deep pipeline, SINGLE barrier/K-step ----------------
// Body: vmcnt(4) -> s_barrier -> stage(kk+2) -> ds_read -> MFMA -> lgkmcnt(0).
// Own-wave lgkmcnt(0) + the single barrier guarantee reads of buf (kk-1)%3 retired
// before any wave restages it. Q TRANSPOSED [bh][d][s] scaled 0.125*log2(e);
// K [bh][s][d]; V transposed [bh][d][s].
__global__ __launch_bounds__(256, 3) void gemm_qkv(const __bf16* __restrict__ A,
                                                   const __bf16* __restrict__ BT,
                                                   const float* __restrict__ bias,
                                                   __bf16* __restrict__ qt, __bf16* __restrict__ kb,
                                                   __bf16* __restrict__ vb) {
  __shared__ __bf16 As[3][128 * 32];
  __shared__ __bf16 Bs[3][128 * 32];
  const int Kdim = D_MODEL;
  const int tid  = threadIdx.x;
  const int lane = tid & 63, wave = tid >> 6;
  const int lr = lane & 15, lg = lane >> 4;
  const int wm = (wave >> 1) * 64, wn = (wave & 1) * 64;

  const int f   = blockIdx.x;
  const int swz = (f & 7) * 96 + (f >> 3);
  const int m0  = (swz / 24) * 128, n0 = (swz % 24) * 128;

  const int srow = tid >> 2, scol = (tid & 3) * 8;

  f32x4 acc[4][4] = {};

  const __bf16* aSrc = A  + (size_t)(m0 + srow) * Kdim + scol;
  const __bf16* bSrc = BT + (size_t)(n0 + srow) * Kdim + scol;

  auto stage = [&](int p, int k0) {
    __builtin_amdgcn_global_load_lds((glb_u32*)(aSrc + k0),              (lds_u32*)(As[p] + wave * 512),        16, 0, 0);
    __builtin_amdgcn_global_load_lds((glb_u32*)(aSrc + 64 * Kdim + k0), (lds_u32*)(As[p] + wave * 512 + 2048), 16, 0, 0);
    __builtin_amdgcn_global_load_lds((glb_u32*)(bSrc + k0),              (lds_u32*)(Bs[p] + wave * 512),        16, 0, 0);
    __builtin_amdgcn_global_load_lds((glb_u32*)(bSrc + 64 * Kdim + k0), (lds_u32*)(Bs[p] + wave * 512 + 2048), 16, 0, 0);
  };

  const int nk = Kdim / 32;
  stage(0, 0);
  stage(1, 32);
  for (int kk = 0; kk < nk; ++kk) {
    const int cur = kk % 3;
    if (kk + 1 < nk) {
      asm volatile("s_waitcnt vmcnt(4)" ::: "memory");   // buf kk landed; kk+1 in flight
    } else {
      asm volatile("s_waitcnt vmcnt(0)" ::: "memory");
    }
    __builtin_amdgcn_s_barrier();
    if (kk + 2 < nk) stage((kk + 2) % 3, (kk + 2) * 32); // overwrites buf read at kk-1 (retired)

    bf16x8 af[4], bfv[4];
#pragma unroll
    for (int i = 0; i < 4; ++i) af[i]  = *reinterpret_cast<const bf16x8*>(&As[cur][(wm + i * 16 + lr) * 32 + lg * 8]);
#pragma unroll
    for (int j = 0; j < 4; ++j) bfv[j] = *reinterpret_cast<const bf16x8*>(&Bs[cur][(wn + j * 16 + lr) * 32 + lg * 8]);
#pragma unroll
    for (int i = 0; i < 4; ++i)
#pragma unroll
      for (int j = 0; j < 4; ++j)
        acc[i][j] = __builtin_amdgcn_mfma_f32_16x16x32_bf16(af[i], bfv[j], acc[i][j], 0, 0, 0);

    asm volatile("s_waitcnt lgkmcnt(0)" ::: "memory");   // this wave's reads of buf cur retired
  }

  const int reg = n0 >> 10;
  if (reg != 1) {
    __bf16* dst = (reg == 0) ? qt : vb;
    const float scl = (reg == 0) ? 0.18033688011112042f : 1.0f;   // 0.125*log2(e) for Q
#pragma unroll
    for (int j = 0; j < 4; ++j) {
      const int gc = n0 + wn + j * 16 + lr;
      const float bv = bias[gc];
      const int rem = gc & 1023, h = rem >> 6, d = rem & 63;
#pragma unroll
      for (int i = 0; i < 4; ++i) {
        const int gr0 = m0 + wm + i * 16 + lg * 4;
        const int b = gr0 >> 11, s0 = gr0 & 2047;
        bf16x4 v4;
#pragma unroll
        for (int ii = 0; ii < 4; ++ii) v4[ii] = (__bf16)((acc[i][j][ii] + bv) * scl);
        *reinterpret_cast<bf16x4*>(&dst[(((size_t)(b * NH + h)) * HD + d) * SEQ + s0]) = v4;
      }
    }
  } else {
#pragma unroll
    for (int i = 0; i < 4; ++i) {
#pragma unroll
      for (int j = 0; j < 4; ++j) {
        const int gc = n0 + wn + j * 16 + lr;
        const float bv = bias[gc];
        const int rem = gc & 1023, h = rem >> 6, d = rem & 63;
#pragma unroll
        for (int ii = 0; ii < 4; ++ii) {
          const int gr = m0 + wm + i * 16 + lg * 4 + ii;
          const int b = gr >> 11, s = gr & 2047;
          kb[(((size_t)(b * NH + h)) * SEQ + s) * HD + d] = (__bf16)(acc[i][j][ii] + bv);
        }
      }
    }
  }
}

// ---------------- proj GEMM: 64x128 tile, BK=32, 3-deep, SINGLE barrier/K-step ----------------
__global__ __launch_bounds__(256, 4) void gemm_proj(const __bf16* __restrict__ A,
                                                    const __bf16* __restrict__ BT,
                                                    const float* __restrict__ bias,
                                                    float* __restrict__ fout) {
  __shared__ __bf16 As[3][64 * 32];
  __shared__ __bf16 Bs[3][128 * 32];
  const int Kdim = D_MODEL;
  const int tid  = threadIdx.x;
  const int lane = tid & 63, wave = tid >> 6;
  const int lr = lane & 15, lg = lane >> 4;
  const int wm = (wave >> 1) * 32, wn = (wave & 1) * 64;
  const int n0 = blockIdx.x * 128, m0 = blockIdx.y * 64;
  const int srow = tid >> 2, scol = (tid & 3) * 8;

  f32x4 acc[2][4] = {};

  const __bf16* aSrc = A  + (size_t)(m0 + srow) * Kdim + scol;
  const __bf16* bSrc = BT + (size_t)(n0 + srow) * Kdim + scol;

  auto stage = [&](int p, int k0) {
    __builtin_amdgcn_global_load_lds((glb_u32*)(aSrc + k0),              (lds_u32*)(As[p] + wave * 512),        16, 0, 0);
    __builtin_amdgcn_global_load_lds((glb_u32*)(bSrc + k0),              (lds_u32*)(Bs[p] + wave * 512),        16, 0, 0);
    __builtin_amdgcn_global_load_lds((glb_u32*)(bSrc + 64 * Kdim + k0), (lds_u32*)(Bs[p] + wave * 512 + 2048), 16, 0, 0);
  };

  const int nk = Kdim / 32;
  stage(0, 0);
  stage(1, 32);
  for (int kk = 0; kk < nk; ++kk) {
    const int cur = kk % 3;
    if (kk + 1 < nk) {
      asm volatile("s_waitcnt vmcnt(3)" ::: "memory");
    } else {
      asm volatile("s_waitcnt vmcnt(0)" ::: "memory");
    }
    __builtin_amdgcn_s_barrier();
    if (kk + 2 < nk) stage((kk + 2) % 3, (kk + 2) * 32);

    bf16x8 af[2], bfv[4];
#pragma unroll
    for (int i = 0; i < 2; ++i) af[i]  = *reinterpret_cast<const bf16x8*>(&As[cur][(wm + i * 16 + lr) * 32 + lg * 8]);
#pragma unroll
    for (int j = 0; j < 4; ++j) bfv[j] = *reinterpret_cast<const bf16x8*>(&Bs[cur][(wn + j * 16 + lr) * 32 + lg * 8]);
#pragma unroll
    for (int i = 0; i < 2; ++i)
#pragma unroll
      for (int j = 0; j < 4; ++j)
        acc[i][j] = __builtin_amdgcn_mfma_f32_16x16x32_bf16(af[i], bfv[j], acc[i][j], 0, 0, 0);

    asm volatile("s_waitcnt lgkmcnt(0)" ::: "memory");
  }

#pragma unroll
  for (int i = 0; i < 2; ++i) {
#pragma unroll
    for (int j = 0; j < 4; ++j) {
      const int gc = n0 + wn + j * 16 + lr;
      const float bv = bias[gc];
#pragma unroll
      for (int ii = 0; ii < 4; ++ii) {
        const int gr = m0 + wm + i * 16 + lg * 4 + ii;
        fout[(size_t)gr * D_MODEL + gc] = acc[i][j][ii] + bv;
      }
    }
  }
}

// ---------------- causal flash attention: 4 waves/block, QBLK=64, SWAPPED QK^T (R25-exact) ----------------
__global__ __launch_bounds__(256, 4) void attn_kernel(const __bf16* __restrict__ QT,
                                                      const __bf16* __restrict__ K,
                                                      const __bf16* __restrict__ VT,
                                                      __bf16* __restrict__ AO) {
  __shared__ __bf16 Kb[2][64 * 64];
  __shared__ __bf16 Vb[2][64 * 64];
  __shared__ __bf16 Ps[4][16 * 64];

  const int tid  = threadIdx.x;
  const int lane = tid & 63, wave = tid >> 6;
  const int lr = lane & 15, lg = lane >> 4;

  const int f  = blockIdx.x;
  const int c  = f & 7;
  const int u  = f >> 3;
  const int bh = c * 4 + (u & 3);
  const int s2 = u >> 2, grp = s2 >> 3, r = s2 & 7;
  const int qblk = (grp == 0) ? (31 - r) : (grp == 1) ? r : (grp == 2) ? (39 - s2) : (s2 - 16);

  const int q0 = qblk * 64 + wave * 16;
  const size_t base = (size_t)bh * SEQ * HD;
  const char* Kg  = (const char*)(K + base);
  const char* VTg = (const char*)(VT + base);

  bf16x8 qf[2];
#pragma unroll
  for (int kc = 0; kc < 2; ++kc) {
    bf16x8 v;
#pragma unroll
    for (int j = 0; j < 8; ++j)
      v[j] = QT[base + (size_t)(kc * 32 + lg * 8 + j) * SEQ + q0 + lr];
    qf[kc] = v;
  }

  int pWr[4];
#pragma unroll
  for (int n = 0; n < 4; ++n)
    pWr[n] = lr * 64 + (((n * 2 + (lg >> 1)) ^ (lr & 7)) << 3) + (lg & 1) * 4;

  float lsum = 0.f;
  f32x4 o[4] = {};

  const int nt = qblk + 1;
  const int nmaxF = (wave | 1) + 1;

  auto stage = [&](int bufp, int t) {
    const int k0 = t * 64;
#pragma unroll
    for (int p = 0; p < 2; ++p) {
      const int row = wave * 16 + p * 8 + (lane >> 3);
      {
        const int srcOff = (k0 + row) * 128 + (((lane & 7) ^ (row & 7)) << 4);
        __builtin_amdgcn_global_load_lds((glb_u32*)(Kg + srcOff),
                                         (lds_u32*)&Kb[bufp][(wave * 16 + p * 8) * 64], 16, 0, 0);
      }
      {
        const int srcOff = row * 4096 + k0 * 2 + (((lane & 7) ^ (row & 7)) << 4);
        __builtin_amdgcn_global_load_lds((glb_u32*)(VTg + srcOff),
                                         (lds_u32*)&Vb[bufp][(wave * 16 + p * 8) * 64], 16, 0, 0);
      }
    }
  };

  stage(0, 0);
  asm volatile("s_waitcnt vmcnt(0)" ::: "memory");
  __syncthreads();

  for (int t = 0; t < nt; ++t) {
    const int p = t & 1;
    const int k0 = t * 64;
    const bool last = (t == nt - 1);
    const int nmax = last ? nmaxF : 4;
    const int kcmax = nmax >> 1;

    if (t + 1 < nt) stage(p ^ 1, t + 1);

    const __bf16* Kt = Kb[p];
    const __bf16* Vt = Vb[p];

    f32x4 s[4] = {};
    __builtin_amdgcn_s_setprio(1);
#pragma unroll
    for (int kc = 0; kc < 2; ++kc) {
#pragma unroll
      for (int n = 0; n < 4; ++n)
        if (n < nmax) {
          bf16x8 kf = *reinterpret_cast<const bf16x8*>(
              &Kt[(n * 16 + lr) * 64 + (((kc * 4 + lg) ^ (lr & 7)) << 3)]);
          s[n] = __builtin_amdgcn_mfma_f32_16x16x32_bf16(kf, qf[kc], s[n], 0, 0, 0);
        }
    }
    __builtin_amdgcn_s_setprio(0);

    if (last) {
      const int qg = q0 + lr;
#pragma unroll
      for (int n = 0; n < 4; ++n)
        if (n < nmax)
#pragma unroll
          for (int ii = 0; ii < 4; ++ii) {
            int kg = k0 + n * 16 + lg * 4 + ii;
            if (kg > qg) s[n][ii] = -__builtin_inff();
          }
    }

#pragma unroll
    for (int n = 0; n < 4; ++n)
      if (n < nmax) {
        bf16x4 pv4;
#pragma unroll
        for (int ii = 0; ii < 4; ++ii) {
          float pv = __builtin_amdgcn_exp2f(s[n][ii]);
          lsum += pv;
          pv4[ii] = (__bf16)pv;
        }
        *reinterpret_cast<bf16x4*>(&Ps[wave][pWr[n]]) = pv4;
      }

    __builtin_amdgcn_s_setprio(1);
#pragma unroll
    for (int kc = 0; kc < 2; ++kc)
      if (kc < kcmax) {
        bf16x8 pa = *reinterpret_cast<const bf16x8*>(
            &Ps[wave][lr * 64 + (((kc * 4 + lg) ^ (lr & 7)) << 3)]);
#pragma unroll
        for (int nd = 0; nd < 4; ++nd) {
          bf16x8 vf = *reinterpret_cast<const bf16x8*>(
              &Vt[(nd * 16 + lr) * 64 + (((kc * 4 + lg) ^ (lr & 7)) << 3)]);
          o[nd] = __builtin_amdgcn_mfma_f32_16x16x32_bf16(pa, vf, o[nd], 0, 0, 0);
        }
      }
    __builtin_amdgcn_s_setprio(0);

    asm volatile("s_waitcnt vmcnt(0)" ::: "memory");
    __syncthreads();
  }

  lsum += __shfl_xor(lsum, 16, 64);
  lsum += __shfl_xor(lsum, 32, 64);

  const int b = bh >> 4, h = bh & 15;
  float rl[4];
#pragma unroll
  for (int ii = 0; ii < 4; ++ii)
    rl[ii] = 1.f / __shfl(lsum, lg * 4 + ii, 64);

#pragma unroll
  for (int nd = 0; nd < 4; ++nd)
#pragma unroll
    for (int ii = 0; ii < 4; ++ii) {
      int row = q0 + lg * 4 + ii;
      AO[((size_t)(b * SEQ) + row) * D_MODEL + h * HD + nd * 16 + lr] = (__bf16)(o[nd][ii] * rl[ii]);
    }
}

// ---------------- launch ----------------
extern "C" void kernel_launch(void* const* d_in, const int* in_sizes, int n_in,
                              void* d_out, int out_size, void* d_ws, size_t ws_size,
                              hipStream_t stream) {
  const float* x      = (const float*)d_in[0];
  const float* w_qkv  = (const float*)d_in[1];
  const float* b_qkv  = (const float*)d_in[2];
  const float* w_proj = (const float*)d_in[3];
  const float* b_proj = (const float*)d_in[4];
  float* out = (float*)d_out;

  char* ws = (char*)d_ws;
  __bf16* xb     = (__bf16*)(ws);                    // 8 MiB
  __bf16* wqkvT  = (__bf16*)(ws + 8388608);          // 6 MiB
  __bf16* wprojT = (__bf16*)(ws + 14680064);         // 2 MiB
  __bf16* qtb    = (__bf16*)(ws + 16777216);         // 8 MiB (transposed Q)
  __bf16* kb     = (__bf16*)(ws + 25165824);         // 8 MiB
  __bf16* vtb    = (__bf16*)(ws + 33554432);         // 8 MiB (transposed V)
  __bf16* ao     = (__bf16*)(ws + 41943040);         // 8 MiB

  prep_kernel<<<5120, 256, 0, stream>>>(x, w_qkv, w_proj, xb, wqkvT, wprojT);

  gemm_qkv<<<768, 256, 0, stream>>>(xb, wqkvT, b_qkv, qtb, kb, vtb);

  attn_kernel<<<1024, 256, 0, stream>>>(qtb, kb, vtb, ao);

  gemm_proj<<<dim3(D_MODEL / 128, M_TOK / 64), 256, 0, stream>>>(
      ao, wprojT, b_proj, out);
}